// Round 1
// baseline (521.881 us; speedup 1.0000x reference)
//
#include <hip/hip_runtime.h>

#define NN 16384
#define MM 16384
#define DD 8
#define DV 16
#define SPLIT 16
#define CHUNK (MM / SPLIT)  // 1024 columns per block

// Precompute sy[j] = sum_d ls_d * y_jd^2  (tiny: 64 KB into d_ws)
__global__ __launch_bounds__(256) void prep_sy(const float* __restrict__ ls,
                                               const float* __restrict__ y,
                                               float* __restrict__ sy) {
    int j = blockIdx.x * 256 + threadIdx.x;
    float s = 0.f;
#pragma unroll
    for (int d = 0; d < DD; ++d) {
        float yv = y[j * DD + d];
        s = fmaf(ls[d] * yv, yv, s);
    }
    sy[j] = s;
}

// One x-row per thread; each block handles 256 rows x one M-chunk of 1024.
// d2 = sx + sy_j - 2 * sum_d (ls_d x_d) y_jd   (8 FMA dot instead of 24-op direct form)
__global__ __launch_bounds__(256) void matern_main(const float* __restrict__ ls,
                                                   const float* __restrict__ x,
                                                   const float* __restrict__ y,
                                                   const float* __restrict__ b,
                                                   const float* __restrict__ sy,
                                                   float* __restrict__ out) {
    const int i = blockIdx.x * 256 + threadIdx.x;
    const int jbeg = blockIdx.y * CHUNK;

    // per-thread: xls_d = ls_d * x_d, sx = sum ls_d x_d^2
    float xls[DD];
    float sx = 0.f;
#pragma unroll
    for (int d = 0; d < DD; ++d) {
        float xv = x[(size_t)i * DD + d];
        float l = ls[d];
        float xl = l * xv;
        xls[d] = xl;
        sx = fmaf(xl, xv, sx);
    }

    const float c1 = 2.23606797749979f;        // sqrt(5)
    const float c2 = 1.2909944487358056f;      // sqrt(5/3)  (as in reference)
    const float c3 = -3.2259641843312987f;     // -sqrt(5) * log2(e): exp(-c1 r) = 2^(c3 r)

    float acc[DV];
#pragma unroll
    for (int v = 0; v < DV; ++v) acc[v] = 0.f;

    const float* yp = y + (size_t)jbeg * DD;
    const float* bp = b + (size_t)jbeg * DV;
    const float* syp = sy + jbeg;

#pragma unroll 2
    for (int j = 0; j < CHUNK; ++j) {
        float dot = 0.f;
#pragma unroll
        for (int d = 0; d < DD; ++d) dot = fmaf(xls[d], yp[j * DD + d], dot);
        float d2 = fmaf(-2.f, dot, sx + syp[j]);
        d2 = fmaxf(d2, 0.f);                       // expansion can round slightly negative
        float r = __builtin_amdgcn_sqrtf(d2);
        float e = __builtin_amdgcn_exp2f(c3 * r);  // v_exp_f32
        float k = fmaf(c2, d2, fmaf(c1, r, 1.f)) * e;
#pragma unroll
        for (int v = 0; v < DV; ++v) acc[v] = fmaf(k, bp[j * DV + v], acc[v]);
    }

    float* op = out + (size_t)i * DV;
#pragma unroll
    for (int v = 0; v < DV; ++v) atomicAdd(op + v, acc[v]);
}

extern "C" void kernel_launch(void* const* d_in, const int* in_sizes, int n_in,
                              void* d_out, int out_size, void* d_ws, size_t ws_size,
                              hipStream_t stream) {
    const float* ls = (const float*)d_in[0];
    const float* x  = (const float*)d_in[1];
    const float* y  = (const float*)d_in[2];
    const float* b  = (const float*)d_in[3];
    float* out = (float*)d_out;
    float* sy  = (float*)d_ws;   // 16384 floats = 64 KB scratch

    hipMemsetAsync(d_out, 0, (size_t)out_size * sizeof(float), stream);
    prep_sy<<<MM / 256, 256, 0, stream>>>(ls, y, sy);
    matern_main<<<dim3(NN / 256, SPLIT), 256, 0, stream>>>(ls, x, y, b, sy, out);
}